// Round 7
// baseline (112.365 us; speedup 1.0000x reference)
//
#include <hip/hip_runtime.h>
#include <hip/hip_bf16.h>

typedef float f32x4  __attribute__((ext_vector_type(4)));
typedef float f32x16 __attribute__((ext_vector_type(16)));
typedef short s16x8  __attribute__((ext_vector_type(8)));
typedef unsigned int u32;

#define NB 4
#define NC 128
#define NNPOS 4096
#define LOG2E 1.44269504088896f

__device__ __forceinline__ short bf16s(float x) {
    __hip_bfloat16 h = __float2bfloat16(x);
    return *reinterpret_cast<short*>(&h);
}
__device__ __forceinline__ int packbf2(float lo, float hi) {
    __hip_bfloat162 t = __float22bfloat162_rn(float2{lo, hi});
    return *reinterpret_cast<int*>(&t);
}
__device__ __forceinline__ float exp2fast(float x) {
    return __builtin_amdgcn_exp2f(x);   // native v_exp_f32 (base 2)
}

// exp2 + pack one 16-score vector into two PV A-frags.
// Consumes sv immediately (score regs die before the next score MFMA
// issues -> peak score liveness 16 regs). lp add order as R12/R14/R15.
__device__ __forceinline__ void exppack(const f32x16& sv, s16x8& plo, s16x8& phi,
                                        float& l0, float& l1) {
    union { int i[4]; s16x8 v; } u;
    #pragma unroll
    for (int j = 0; j < 4; ++j) {
        float p0 = exp2fast(sv[2 * j]);
        float p1 = exp2fast(sv[2 * j + 1]);
        if (j & 1) l1 += p0 + p1; else l0 += p0 + p1;
        u.i[j] = packbf2(p0, p1);
    }
    plo = u.v;
    #pragma unroll
    for (int j = 0; j < 4; ++j) {
        float p0 = exp2fast(sv[8 + 2 * j]);
        float p1 = exp2fast(sv[8 + 2 * j + 1]);
        if (j & 1) l1 += p0 + p1; else l0 += p0 + p1;
        u.i[j] = packbf2(p0, p1);
    }
    phi = u.v;
}

// ------------------------------------------------------------------
// Kernel 1: QKV projection via bf16 MFMA 16x16x32 (unchanged from R15).
// vt layout: lane-linear order:
//   short_idx = ((b*256+kg)*4 + ct)*512 + (slot>>3)*256 + (c&31)*8 + (slot&7)
// slot = swap-bits-2,3 of (key%16). Attn lane l reads its PV B-frag at
// exactly l*8 shorts within each (kg,ct) 1KB slab -> dense coalescing.
// ------------------------------------------------------------------
__global__ __launch_bounds__(256) void qkv_kernel(
    const float* __restrict__ x,
    const float* __restrict__ wq, const float* __restrict__ bq,
    const float* __restrict__ wk, const float* __restrict__ bk,
    const float* __restrict__ wv, const float* __restrict__ bv,
    short* __restrict__ qb, short* __restrict__ kb, short* __restrict__ vt)
{
    const int n0  = blockIdx.x * 32;
    const int b   = blockIdx.y;
    const int tid = threadIdx.x;
    const int w = tid >> 6, lane = tid & 63, quad = lane >> 4, nn = lane & 15;

    __shared__ __align__(16) short xsT[32 * 136];
    __shared__ __align__(16) short vstage[4096];   // 2 kg x 4 ct x 512

    #pragma unroll
    for (int p = 0; p < 4; ++p) {
        int idx = tid + p * 256;
        int cc = idx >> 3, n4 = (idx & 7) * 4;
        f32x4 xv = *(const f32x4*)&x[((size_t)(b * NC + cc)) * NNPOS + n0 + n4];
        #pragma unroll
        for (int j = 0; j < 4; ++j)
            xsT[(n4 + j) * 136 + cc] = bf16s(xv[j]);
    }

    s16x8 af[3][4];
    bool  live[3];
    f32x4 biasv[3];
    #pragma unroll
    for (int t = 0; t < 3; ++t) {
        int rid = 3 * w + t;
        int R   = rid * 16;
        const float* wsrc = nullptr; const float* bsrc = nullptr; int row0 = 0;
        float scale = 1.0f;
        if (rid < 8)        { wsrc = wv; bsrc = bv; row0 = R; }
        else if (rid == 8)  { wsrc = wq; bsrc = bq; row0 = 0; scale = LOG2E; }
        else if (rid == 10) { wsrc = wk; bsrc = bk; row0 = 0; }
        live[t] = (wsrc != nullptr);
        #pragma unroll
        for (int r = 0; r < 4; ++r)
            biasv[t][r] = live[t] ? scale * bsrc[row0 + quad * 4 + r] : 0.0f;
        if (live[t]) {
            #pragma unroll
            for (int ks = 0; ks < 4; ++ks) {
                const float* src = wsrc + (size_t)(row0 + nn) * NC + ks * 32 + quad * 8;
                f32x4 wa = *(const f32x4*)src;
                f32x4 wb = *(const f32x4*)(src + 4);
                s16x8 f;
                #pragma unroll
                for (int j = 0; j < 4; ++j) {
                    f[j]     = bf16s(scale * wa[j]);
                    f[j + 4] = bf16s(scale * wb[j]);
                }
                af[t][ks] = f;
            }
        }
    }
    __syncthreads();

    f32x4 acc[3][2];
    #pragma unroll
    for (int t = 0; t < 3; ++t)
        #pragma unroll
        for (int nt = 0; nt < 2; ++nt)
            acc[t][nt] = biasv[t];

    #pragma unroll
    for (int nt = 0; nt < 2; ++nt) {
        s16x8 bf[4];
        #pragma unroll
        for (int ks = 0; ks < 4; ++ks)
            bf[ks] = *(const s16x8*)&xsT[(nt * 16 + nn) * 136 + ks * 32 + quad * 8];
        #pragma unroll
        for (int t = 0; t < 3; ++t)
            if (live[t])
                #pragma unroll
                for (int ks = 0; ks < 4; ++ks)
                    acc[t][nt] = __builtin_amdgcn_mfma_f32_16x16x32_bf16(af[t][ks], bf[ks], acc[t][nt], 0, 0, 0);
    }

    // V-slot key permutation: swap bits 2<->3 of (key%16)
    const int slot = (nn & 3) | ((nn & 4) << 1) | ((nn & 8) >> 1);

    #pragma unroll
    for (int t = 0; t < 3; ++t) {
        if (!live[t]) continue;
        const int rid = 3 * w + t;
        #pragma unroll
        for (int nt = 0; nt < 2; ++nt) {
            if (rid < 8) {
                #pragma unroll
                for (int r = 0; r < 4; ++r) {
                    int row = rid * 16 + quad * 4 + r;
                    vstage[(((nt << 2) | (row >> 5)) << 9) +
                           ((slot >> 3) << 8) + ((row & 31) << 3) + (slot & 7)]
                        = bf16s(acc[t][nt][r]);
                }
            } else {
                short4 pk;
                pk.x = bf16s(acc[t][nt][0]);
                pk.y = bf16s(acc[t][nt][1]);
                pk.z = bf16s(acc[t][nt][2]);
                pk.w = bf16s(acc[t][nt][3]);
                int n = n0 + nt * 16 + nn;
                short* dst = (rid == 8 ? qb : kb) +
                             ((size_t)(b * NNPOS) + n) * 16 + quad * 4;
                *reinterpret_cast<short4*>(dst) = pk;
            }
        }
    }
    __syncthreads();

    // coalesced copy-out: 8 KB tile, 256 threads x 2 x 16B
    {
        short* vdst = vt + ((size_t)(b * 256) + (n0 >> 4)) * 2048;
        #pragma unroll
        for (int p = 0; p < 2; ++p) {
            int off = (tid + p * 256) * 8;
            *(s16x8*)&vdst[off] = *(const s16x8*)&vstage[off];
        }
    }
}

// ------------------------------------------------------------------
// Kernel 2 (R16): single-pass attention, in-block key split (R15) +
// full V software pipeline + setprio on PV clusters.
// Pipeline: vb23[it] issued at iter TOP (consumed after scores+exp+PV01,
// ~500cy later); vb01[it+1] issued between PV01 and PV23 (consumed
// ~700cy later). No V load consumed < ~400cy after issue -> L2 latency
// covered. Reg peak ~180 < 256 @ 2 waves/SIMD (T14: compute phase long
// enough to hide HBM/L2 latency).
// setprio around PV MFMAs: barrier-free main loop -> waves phase-
// diverse -> m191-positive regime (unlike barriered R10 variant).
// Block = one 32-query tile x ALL 4096 keys; wave w: keys [w*1024, +1024).
// fp32 partials combined at block end via 2-round LDS tree; epilogue
// applies 1/sum(l), gamma, +x; writes out directly.
// ------------------------------------------------------------------
__global__ __launch_bounds__(256, 2) void attn_kernel(
    const short* __restrict__ qb, const short* __restrict__ kb,
    const short* __restrict__ vt,
    const float* __restrict__ xg, const float* __restrict__ gamma,
    float* __restrict__ out)
{
    const int idx = blockIdx.x;
    const int b   = (idx & 7) >> 1;                    // XCD-pinned batch
    const int qy  = ((idx >> 3) << 1) | (idx & 1);     // 0..127
    const int q0  = qy * 32;
    const int tid = threadIdx.x;
    const int w = tid >> 6, lane = tid & 63, h = lane >> 5, c31 = lane & 31;

    // combine tree buffers: 2 x [128 c][33 q-padded] + lp + inv  (~34.4 KB)
    __shared__ float cbufA[128][33];
    __shared__ float cbufB[128][33];
    __shared__ float lpbuf[4][32];
    __shared__ float invbuf[32];

    s16x8 bq = *(const s16x8*)(qb + ((size_t)(b * NNPOS) + q0 + c31) * 16 + h * 8);

    f32x16 acc[4];
    #pragma unroll
    for (int ct = 0; ct < 4; ++ct)
        #pragma unroll
        for (int r = 0; r < 16; ++r) acc[ct][r] = 0.0f;
    float lp0 = 0.f, lp1 = 0.f;

    const short* kbp = kb + (size_t)(b * NNPOS) * 16;
    const short* vbp = vt + (size_t)b * (NC * NNPOS);

    f32x16 z;
    #pragma unroll
    for (int r = 0; r < 16; ++r) z[r] = 0.0f;

    // wave's private 1024-key slice
    const int kgb = w * 64;            // key-group base (1024/16)
    int m0 = w * 1024;
    s16x8 ak0 = *(const s16x8*)(kbp + (size_t)(m0      + c31) * 16 + h * 8);
    s16x8 ak1 = *(const s16x8*)(kbp + (size_t)(m0 + 32 + c31) * 16 + h * 8);

    // prologue: V groups 0,1 of iter 0
    s16x8 vb01[2][4];
    #pragma unroll
    for (int p = 0; p < 2; ++p)
        #pragma unroll
        for (int ct = 0; ct < 4; ++ct)
            vb01[p][ct] = *(const s16x8*)(vbp +
                (((size_t)(kgb + p) * 4 + ct) << 9) + (lane << 3));

    #pragma unroll 1
    for (int it = 0; it < 16; ++it) {
        const int kg0 = kgb + it * 4;

        // issue V groups 2,3 NOW (consumed after scores+exp+PV01)
        s16x8 vb23[2][4];
        #pragma unroll
        for (int p = 0; p < 2; ++p)
            #pragma unroll
            for (int ct = 0; ct < 4; ++ct)
                vb23[p][ct] = *(const s16x8*)(vbp +
                    (((size_t)(kg0 + 2 + p) * 4 + ct) << 9) + (lane << 3));

        // scores -> exp/pack (sequential: 16-score liveness)
        s16x8 pa[4];
        {
            f32x16 sc = __builtin_amdgcn_mfma_f32_32x32x16_bf16(ak0, bq, z, 0, 0, 0);
            exppack(sc, pa[0], pa[1], lp0, lp1);
            sc = __builtin_amdgcn_mfma_f32_32x32x16_bf16(ak1, bq, z, 0, 0, 0);
            exppack(sc, pa[2], pa[3], lp0, lp1);
        }

        // prefetch next iter's K (ak0/ak1 dead after the score MFMAs)
        if (it + 1 < 16) {
            m0 += 64;
            ak0 = *(const s16x8*)(kbp + (size_t)(m0      + c31) * 16 + h * 8);
            ak1 = *(const s16x8*)(kbp + (size_t)(m0 + 32 + c31) * 16 + h * 8);
        }

        // PV groups 0,1
        __builtin_amdgcn_s_setprio(1);
        #pragma unroll
        for (int p = 0; p < 2; ++p)
            #pragma unroll
            for (int ct = 0; ct < 4; ++ct)
                acc[ct] = __builtin_amdgcn_mfma_f32_32x32x16_bf16(
                    pa[p], vb01[p][ct], acc[ct], 0, 0, 0);
        __builtin_amdgcn_s_setprio(0);

        // prefetch NEXT iter's V groups 0,1 (consumed after PV23 + next
        // scores/exp: ~700cy of cover)
        if (it + 1 < 16) {
            #pragma unroll
            for (int p = 0; p < 2; ++p)
                #pragma unroll
                for (int ct = 0; ct < 4; ++ct)
                    vb01[p][ct] = *(const s16x8*)(vbp +
                        (((size_t)(kg0 + 4 + p) * 4 + ct) << 9) + (lane << 3));
        }

        // PV groups 2,3
        __builtin_amdgcn_s_setprio(1);
        #pragma unroll
        for (int p = 0; p < 2; ++p)
            #pragma unroll
            for (int ct = 0; ct < 4; ++ct)
                acc[ct] = __builtin_amdgcn_mfma_f32_32x32x16_bf16(
                    pa[2 + p], vb23[p][ct], acc[ct], 0, 0, 0);
        __builtin_amdgcn_s_setprio(0);
    }

    // per-wave l sum for each of the 32 queries
    float lp = lp0 + lp1;
    lp += __shfl_xor(lp, 32, 64);
    if (lane < 32) lpbuf[w][c31] = lp;

    // ---- in-block combine, round 1: w0 -> A, w1 -> B ----
    if (w < 2) {
        float (*cb)[33] = (w == 0) ? cbufA : cbufB;
        #pragma unroll
        for (int ct = 0; ct < 4; ++ct)
            #pragma unroll
            for (int r = 0; r < 16; ++r) {
                int q = (r & 3) + 8 * (r >> 2) + 4 * h;
                cb[ct * 32 + c31][q] = acc[ct][r];
            }
    }
    __syncthreads();

    // ---- round 2: w2 += A, w3 += B; w0 lanes compute 1/sum(l) ----
    if (w >= 2) {
        float (*cb)[33] = (w == 2) ? cbufA : cbufB;
        #pragma unroll
        for (int ct = 0; ct < 4; ++ct)
            #pragma unroll
            for (int r = 0; r < 16; ++r) {
                int q = (r & 3) + 8 * (r >> 2) + 4 * h;
                cb[ct * 32 + c31][q] += acc[ct][r];
            }
    }
    if (tid < 32)
        invbuf[tid] = 1.0f / (lpbuf[0][tid] + lpbuf[1][tid] +
                              lpbuf[2][tid] + lpbuf[3][tid]);
    __syncthreads();

    // ---- epilogue: out[b][c][q0+q] = g*(A+B)*inv + x ----
    {
        const float g = gamma[0];
        const int c  = tid >> 1;
        const int nh = (tid & 1) * 16;
        size_t base = ((size_t)(b * NC + c)) * NNPOS + q0 + nh;
        #pragma unroll
        for (int j = 0; j < 16; j += 4) {
            f32x4 xv = *(const f32x4*)&xg[base + j];
            f32x4 o;
            #pragma unroll
            for (int e = 0; e < 4; ++e) {
                int q = nh + j + e;
                o[e] = g * (cbufA[c][q] + cbufB[c][q]) * invbuf[q] + xv[e];
            }
            *(f32x4*)&out[base + j] = o;
        }
    }
}

// ------------------------------------------------------------------
extern "C" void kernel_launch(void* const* d_in, const int* in_sizes, int n_in,
                              void* d_out, int out_size, void* d_ws, size_t ws_size,
                              hipStream_t stream) {
    const float* x     = (const float*)d_in[0];
    const float* wq    = (const float*)d_in[1];
    const float* bq    = (const float*)d_in[2];
    const float* wk    = (const float*)d_in[3];
    const float* bk    = (const float*)d_in[4];
    const float* wv    = (const float*)d_in[5];
    const float* bv    = (const float*)d_in[6];
    const float* gamma = (const float*)d_in[7];
    float* out = (float*)d_out;

    // ws: qb 512KB | kb 512KB | vt 4MB
    short* qb = (short*)d_ws;
    short* kb = qb + (size_t)NB * NNPOS * 16;
    short* vt = kb + (size_t)NB * NNPOS * 16;

    qkv_kernel<<<dim3(128, NB), 256, 0, stream>>>(x, wq, bq, wk, bk, wv, bv, qb, kb, vt);
    attn_kernel<<<dim3(512), 256, 0, stream>>>(qb, kb, vt, x, gamma, out);
}